// Round 3
// baseline (17.362 us; speedup 1.0000x reference)
//
#include <hip/hip_runtime.h>

// CRPS loss: forecasts (N, P), observation (P), out (P)
// out[p] = mean_j |x_j - y| - (1-eps) * sum_{j,k} |x_j - x_k| / (2 n (n-1))
// with x = max(forecast, CLIP_VALUE).
//
// Rotation identity: sum_{j,k} |x_j - x_k| = sum_{d=1}^{n-1} sum_j |x_j - x_{(j+d)%n}|
// (each unordered pair hit exactly twice, matching the reference's full-matrix sum).
// 4 waves cooperate per 64 output points: wave w handles d = w+1, w+5, ...
// All member values in registers (compile-time indices only); LDS reduce at end.

constexpr int N = 50;
constexpr int WAVES = 4;
constexpr int BLOCK = 64 * WAVES;
constexpr float CLIP_VALUE = -0.26787253f;
constexpr float EPSILON = 1e-4f;

template <int W>
__device__ __forceinline__ float tri_chunk(const float (&x)[N]) {
    // sum over d in {W+1, W+1+4, ...} of sum_j |x[j] - x[(j+d)%N]|
    float a0 = 0.f, a1 = 0.f, a2 = 0.f, a3 = 0.f;
    #pragma unroll
    for (int d = 1 + W; d < N; d += WAVES) {
        #pragma unroll
        for (int j = 0; j < N; ++j) {
            const int k = (j + d) % N;          // compile-time after unroll
            const float v = fabsf(x[j] - x[k]);
            const int c = j & 3;
            if      (c == 0) a0 += v;
            else if (c == 1) a1 += v;
            else if (c == 2) a2 += v;
            else             a3 += v;
        }
    }
    return (a0 + a1) + (a2 + a3);
}

__global__ __launch_bounds__(BLOCK) void crps_kernel(
    const float* __restrict__ forecasts,    // (N, P)
    const float* __restrict__ observation,  // (P)
    float* __restrict__ out,                // (P)
    int P)
{
    __shared__ float part[WAVES][64];
    __shared__ float t1s[64];

    const int lane = threadIdx.x & 63;
    const int w    = threadIdx.x >> 6;
    const int p    = blockIdx.x * 64 + lane;
    const bool ok  = (p < P);
    const int  pp  = ok ? p : 0;   // clamp; masked lanes' results are discarded

    // All 4 waves load the same 64x50 block; L1 serves the repeats.
    float x[N];
    #pragma unroll
    for (int m = 0; m < N; ++m)
        x[m] = fmaxf(forecasts[m * P + pp], CLIP_VALUE);

    float t2p;
    if      (w == 0) t2p = tri_chunk<0>(x);  // 13 d's
    else if (w == 1) t2p = tri_chunk<1>(x);  // 12 d's
    else if (w == 2) t2p = tri_chunk<2>(x);  // 12 d's
    else             t2p = tri_chunk<3>(x);  // 12 d's + term1 below

    part[w][lane] = t2p;

    if (w == 3) {
        const float y = observation[pp];
        float s0 = 0.f, s1 = 0.f;
        #pragma unroll
        for (int j = 0; j < N; j += 2) {
            s0 += fabsf(x[j] - y);
            if (j + 1 < N) s1 += fabsf(x[j + 1] - y);
        }
        t1s[lane] = s0 + s1;
    }

    __syncthreads();

    if (w == 0 && ok) {
        const float t2 = (part[0][lane] + part[1][lane]) +
                         (part[2][lane] + part[3][lane]);
        const float term1 = t1s[lane] * (1.0f / (float)N);
        const float term2 = t2 * (1.0f / (2.0f * N * (N - 1)));
        out[p] = term1 - (1.0f - EPSILON) * term2;
    }
}

extern "C" void kernel_launch(void* const* d_in, const int* in_sizes, int n_in,
                              void* d_out, int out_size, void* d_ws, size_t ws_size,
                              hipStream_t stream) {
    const float* forecasts   = (const float*)d_in[0];  // (50, 64, 336)
    const float* observation = (const float*)d_in[1];  // (64, 336)
    float* out = (float*)d_out;                        // (64, 336)

    const int P = out_size;  // 21504
    const int grid = (P + 63) / 64;

    crps_kernel<<<grid, BLOCK, 0, stream>>>(forecasts, observation, out, P);
}

// Round 4
// 9.658 us; speedup vs baseline: 1.7976x; 1.7976x over previous
//
#include <hip/hip_runtime.h>
#include <cfloat>

// CRPS loss: forecasts (N, P), observation (P), out (P)
// out[p] = mean_j |x_j - y| - (1-eps) * sum_{j,k} |x_j - x_k| / (2 n (n-1))
// with x = max(forecast, CLIP_VALUE).
//
// Sorted form of the pairwise term (exact identity):
//   tri = sum_{j<k} |x_j - x_k| = sum_i (2i - (n-1)) * x_sorted[i]
//   sum_{j,k} = 2 * tri  ->  term2 = tri / (n (n-1))
// Sort via Batcher odd-even merge network, n padded 50 -> 64 with +FLT_MAX
// (pads sort to the top; real values land ascending in x[0..49]).
// 543 compare-exchanges = 1086 min/max, all register-static. ~1350 VALU
// per thread vs 2450 for the direct triangle. One wave per 64 points,
// uniform code path (~12 KB, fits 32 KB I$ — R3's 40 KB template split
// thrashed it).

constexpr int N = 50;
constexpr int NP = 64;            // padded size (power of 2)
constexpr int BLOCK = 64;
constexpr float CLIP_VALUE = -0.26787253f;
constexpr float EPSILON = 1e-4f;

__global__ __launch_bounds__(BLOCK) void crps_kernel(
    const float* __restrict__ forecasts,    // (N, P)
    const float* __restrict__ observation,  // (P)
    float* __restrict__ out,                // (P)
    int P)
{
    const int p = blockIdx.x * BLOCK + threadIdx.x;
    if (p >= P) return;

    const float y = observation[p];

    float x[NP];

    // Load + clip (coalesced per member); term1 on unsorted values.
    float t1a = 0.0f, t1b = 0.0f;
    #pragma unroll
    for (int m = 0; m < N; ++m) {
        const float v = fmaxf(forecasts[m * P + p], CLIP_VALUE);
        x[m] = v;
        if (m & 1) t1b += fabsf(v - y);
        else       t1a += fabsf(v - y);
    }
    #pragma unroll
    for (int m = N; m < NP; ++m) x[m] = FLT_MAX;   // pad sorts to top

    // Batcher odd-even mergesort, n = 64, ascending.
    #pragma unroll
    for (int pp = 1; pp < NP; pp <<= 1) {
        #pragma unroll
        for (int k = pp; k >= 1; k >>= 1) {
            #pragma unroll
            for (int j = k & (pp - 1); j + k < NP; j += 2 * k) {
                #pragma unroll
                for (int i = 0; i < k; ++i) {
                    if ((i + j) / (2 * pp) == (i + j + k) / (2 * pp)) {
                        const float a = x[i + j];
                        const float b = x[i + j + k];
                        x[i + j]     = fminf(a, b);
                        x[i + j + k] = fmaxf(a, b);
                    }
                }
            }
        }
    }

    // tri = sum_i (2i - 49) * x[i], 4 rotating accumulators
    float sa = 0.f, sb = 0.f, sc = 0.f, sd = 0.f;
    #pragma unroll
    for (int i = 0; i < N; i += 4) {
        sa = fmaf((float)(2 * i     - 49), x[i],     sa);
        if (i + 1 < N) sb = fmaf((float)(2 * (i+1) - 49), x[i + 1], sb);
        if (i + 2 < N) sc = fmaf((float)(2 * (i+2) - 49), x[i + 2], sc);
        if (i + 3 < N) sd = fmaf((float)(2 * (i+3) - 49), x[i + 3], sd);
    }
    const float tri = (sa + sb) + (sc + sd);

    const float term1 = (t1a + t1b) * (1.0f / (float)N);
    const float term2 = tri * (1.0f / (float)(N * (N - 1)));
    out[p] = term1 - (1.0f - EPSILON) * term2;
}

extern "C" void kernel_launch(void* const* d_in, const int* in_sizes, int n_in,
                              void* d_out, int out_size, void* d_ws, size_t ws_size,
                              hipStream_t stream) {
    const float* forecasts   = (const float*)d_in[0];  // (50, 64, 336)
    const float* observation = (const float*)d_in[1];  // (64, 336)
    float* out = (float*)d_out;                        // (64, 336)

    const int P = out_size;  // 21504
    const int grid = (P + BLOCK - 1) / BLOCK;

    crps_kernel<<<grid, BLOCK, 0, stream>>>(forecasts, observation, out, P);
}